// Round 6
// baseline (89.800 us; speedup 1.0000x reference)
//
#include <hip/hip_runtime.h>
#include <hip/hip_bf16.h>
#include <math.h>

#define N_CELLS 65536
#define NH 7
#define NV 4
#define E_IN 16
#define E_OUT 16
#define N_OFF 4
#define N_SIG 4
#define NK 16            // N_OFF * N_SIG

#define CPB 8            // cells per (1-wave) block
#define THREADS 64

typedef __attribute__((ext_vector_type(8))) short bf16x8;
typedef __attribute__((ext_vector_type(4))) float f32x4;

static __device__ __forceinline__ short f2bfs(float f) {
    __hip_bfloat16 h = __float2bfloat16(f);
    short s;
    __builtin_memcpy(&s, &h, 2);
    return s;
}
static __device__ __forceinline__ float b2f(short s) {
    unsigned u = ((unsigned)(unsigned short)s) << 16;
    float f;
    __builtin_memcpy(&f, &u, 4);
    return f;
}

// ---- setup: convert x -> bf16 copy xp (same layout); block 0 also packs W
// into per-lane MFMA B-fragment layout [st][grp][col][j] (bf16).
__global__ __launch_bounds__(256) void setup_kernel(
    const float* __restrict__ x, const float* __restrict__ W,
    short* __restrict__ wf, short* __restrict__ xp)
{
    const int t = threadIdx.x;
    const size_t i = ((size_t)blockIdx.x * 256 + t) * 8;
    const float4* p = (const float4*)(x + i);
    const float4 a = p[0], b = p[1];
    bf16x8 o;
    o[0] = f2bfs(a.x); o[1] = f2bfs(a.y); o[2] = f2bfs(a.z); o[3] = f2bfs(a.w);
    o[4] = f2bfs(b.x); o[5] = f2bfs(b.y); o[6] = f2bfs(b.z); o[7] = f2bfs(b.w);
    *(bf16x8*)(xp + i) = o;

    if (blockIdx.x == 0) {
        const int kk  = t;                 // flat K = k_os*16 + e, 0..255
        const int j   = kk & 7;
        const int grp = (kk >> 3) & 3;
        const int st  = kk >> 5;
        #pragma unroll
        for (int col = 0; col < E_OUT; ++col)
            wf[(((st * 4 + grp) * 16) + col) * 8 + j] = f2bfs(W[kk * E_OUT + col]);
    }
}

__global__ __launch_bounds__(THREADS, 4) void mge_kernel(
    const short* __restrict__ xp,      // bf16 x copy in d_ws
    const float* __restrict__ coords,
    const float* __restrict__ sigma,
    const float* __restrict__ dist_offsets,
    const short* __restrict__ wf,      // packed W fragments in d_ws
    const float* __restrict__ b_out,
    const int*   __restrict__ adjc,
    const int*   __restrict__ nh_mask,
    float* __restrict__ out)
{
    __shared__ float nd_lds[CPB][NK][8];   // 4 KB, padded rows (32B)
    __shared__ int   adj_lds[CPB][NH];
    __shared__ float d_lds[CPB][NH];
    __shared__ float m_lds[CPB][NH];

    const int lane = threadIdx.x;
    const int base = blockIdx.x * CPB;

    // ---- distances: 8 cells x 7 neighbors = 56 tasks ----
    if (lane < CPB * NH) {
        const int cl = lane / NH;
        const int h  = lane % NH;
        const int n  = base + cl;
        const int a  = adjc[n * NH + h];
        const int m  = nh_mask[n * NH + h];
        adj_lds[cl][h] = a;
        const float lat_c = coords[n];
        const float lon_c = coords[N_CELLS + n];
        const float lat_n = coords[a];
        const float lon_n = coords[N_CELLS + a];
        float cosd = sinf(lat_c) * sinf(lat_n) +
                     cosf(lat_c) * cosf(lat_n) * cosf(lon_n - lon_c);
        cosd = fminf(fmaxf(cosd, -1.0f + 1e-7f), 1.0f - 1e-7f);
        d_lds[cl][h] = acosf(cosd);
        m_lds[cl][h] = (float)m;
    }

    // ---- per-lane B fragments from packed global (L2-hot, coalesced) ----
    const int col  = lane & 15;
    const int grp  = lane >> 4;

    bf16x8 bfrag[8];
    #pragma unroll
    for (int st = 0; st < 8; ++st)
        bfrag[st] = ((const bf16x8*)wf)[(st * 4 + grp) * 16 + col];
    const float bias = b_out[col];

    __syncthreads();   // 1-wave block: cheap; orders LDS for nd phase

    // ---- lane roles for main phase ----
    const int cl_in_pair = (lane & 15) >> 3;
    const int bv = lane & 7;
    const int b  = bv >> 2;
    const int v  = bv & 3;
    const int e0 = (grp & 1) * 8;
    const int kos_off = grp >> 1;

    bf16x8 xb[NH];

#define LOADXR(PIDX)                                                            \
    {                                                                           \
        const int cl_ = ((PIDX) << 1) + cl_in_pair;                             \
        _Pragma("unroll")                                                       \
        for (int h = 0; h < NH; ++h) {                                          \
            const int a = adj_lds[cl_][h];                                      \
            xb[h] = *(const bf16x8*)(xp +                                       \
                ((((size_t)b * N_CELLS + a) * NV + v) << 4) + e0);              \
        }                                                                       \
    }

    // prefetch pair 0 now — latency hides under the nd phase
    LOADXR(0)

    // ---- nd weights: 8 cells x 16 (o,s) = 128 tasks, 2/lane ----
    #pragma unroll
    for (int it = 0; it < 2; ++it) {
        const int task = it * THREADS + lane;
        const int cl = task >> 4;
        const int k  = task & 15;          // k = o*N_SIG + s
        const int o  = k >> 2;
        const int s  = k & 3;
        const float off     = dist_offsets[o];
        const float inv_sig = 1.0f / sigma[s];
        float raw[NH];
        float sum = 0.0f;
        #pragma unroll
        for (int h = 0; h < NH; ++h) {
            const float df = (d_lds[cl][h] - off) * inv_sig;
            const float e  = __expf(-0.5f * df * df) * m_lds[cl][h];
            raw[h] = e;
            sum += e;
        }
        const float inv = 1.0f / (sum + 1e-8f);
        #pragma unroll
        for (int h = 0; h < NH; ++h)
            nd_lds[cl][k][h] = raw[h] * inv;
        nd_lds[cl][k][7] = 0.0f;           // pad slot
    }
    __syncthreads();

    // ---- main: 4 pairs, single bf16 buffer, unpack-then-issue-next ----
    #pragma unroll
    for (int p = 0; p < 4; ++p) {
        const int c0_ = p << 1;
        const int cl_ = c0_ + cl_in_pair;

        // unpack current pair to f32 (waits on xb loads, frees xb)
        float xf[NH][8];
        #pragma unroll
        for (int h = 0; h < NH; ++h) {
            #pragma unroll
            for (int j = 0; j < 8; ++j) xf[h][j] = b2f(xb[h][j]);
        }

        // issue next pair's gathers — overlap with this pair's compute
        if (p < 3) LOADXR(p + 1)

        f32x4 acc = {0.f, 0.f, 0.f, 0.f};
        #pragma unroll
        for (int st = 0; st < 8; ++st) {
            const int k2 = st * 2 + kos_off;
            const float4 n0 = *(const float4*)&nd_lds[cl_][k2][0];
            const float4 n1 = *(const float4*)&nd_lds[cl_][k2][4];
            const float nds[NH] = {n0.x, n0.y, n0.z, n0.w, n1.x, n1.y, n1.z};

            bf16x8 aa;
            #pragma unroll
            for (int j = 0; j < 8; ++j) {
                float s = 0.0f;
                #pragma unroll
                for (int h = 0; h < NH; ++h) s += nds[h] * xf[h][j];
                aa[j] = f2bfs(s);
            }
            acc = __builtin_amdgcn_mfma_f32_16x16x32_bf16(aa, bfrag[st], acc, 0, 0, 0);
        }

        // store: D col = lane&15, row = grp*4 + r
        #pragma unroll
        for (int r = 0; r < 4; ++r) {
            const int rr  = grp * 4 + r;
            const int cs  = rr >> 3;
            const int bvs = rr & 7;
            const int bs  = bvs >> 2;
            const int vs  = bvs & 3;
            const int cell = base + c0_ + cs;
            out[((((size_t)bs * N_CELLS + cell) * NV + vs) << 4) + col] = acc[r] + bias;
        }
    }
#undef LOADXR
}

extern "C" void kernel_launch(void* const* d_in, const int* in_sizes, int n_in,
                              void* d_out, int out_size, void* d_ws, size_t ws_size,
                              hipStream_t stream) {
    const float* x            = (const float*)d_in[0];
    const float* coords       = (const float*)d_in[1];
    const float* sigma        = (const float*)d_in[2];
    const float* dist_offsets = (const float*)d_in[3];
    const float* W            = (const float*)d_in[4];
    const float* b_out        = (const float*)d_in[5];
    const int*   adjc         = (const int*)d_in[6];
    const int*   nh_mask      = (const int*)d_in[7];
    float* out = (float*)d_out;

    short* wf = (short*)d_ws;                    // 8 KB packed W fragments
    short* xp = (short*)d_ws + 4096;             // bf16 x copy (16.7 MB)

    const int x_elems   = in_sizes[0];           // 8388608
    const int cv_blocks = x_elems / (256 * 8);   // 4096

    setup_kernel<<<cv_blocks, 256, 0, stream>>>(x, W, wf, xp);
    dim3 grid(N_CELLS / CPB);
    mge_kernel<<<grid, THREADS, 0, stream>>>(xp, coords, sigma, dist_offsets, wf,
                                             b_out, adjc, nh_mask, out);
}